// Round 1
// baseline (200.596 us; speedup 1.0000x reference)
//
#include <hip/hip_runtime.h>

#define BATCH   131072
#define IN_DIM  256
#define OUT_DIM 32
#define N_INNER 255
#define N_LEAF  256
#define OUT_HDR (BATCH * OUT_DIM)

#define TILE_M  64
#define BK      32
#define NTHR    512
#define NCHUNK  8
#define PSTR    260                      // u16 units; 4-row stride = +8 banks -> conflict-free writes
#define INV64K  (1.0f / 65536.0f)

// ---- d_ws layout (bytes) ----
#define WS_QT_HI   0                     // [32 cols][256 leaves] bf16
#define WS_QT_LO   16384
#define WS_WIMG_HI 32768                 // [8 chunk][256 node][4 koct][16B] bf16-hi
#define WS_WIMG_LO (32768 + 131072)      // same layout, bf16-lo

// ---- LDS layout (bytes) ----
// [0, 33280)      prob u16 [64][PSTR]          (phase 1)
// [0, 32768)      P_hi image (overlays prob)   (phase 2, after B1)
// [33792, 66560)  P_lo image                   (exclusive region, written pre-B1)
#define IMG_LO     33792
#define SMEM_BYTES (IMG_LO + 32768)      // 66560 -> 2 blocks/CU

typedef __attribute__((ext_vector_type(8))) short bf16x8;
typedef __attribute__((ext_vector_type(4))) float f32x4;

__device__ __forceinline__ unsigned short bf16rne(float a) {
    unsigned u = __float_as_uint(a);
    return (unsigned short)((u + 0x7FFFu + ((u >> 16) & 1u)) >> 16);
}
__device__ __forceinline__ unsigned packhi2(float a, float b) {
    return (unsigned)bf16rne(a) | ((unsigned)bf16rne(b) << 16);
}
__device__ __forceinline__ unsigned packlo2(float a, float b) {
    unsigned short ha = bf16rne(a), hb = bf16rne(b);
    float ra = a - __uint_as_float((unsigned)ha << 16);
    float rb = b - __uint_as_float((unsigned)hb << 16);
    return (unsigned)bf16rne(ra) | ((unsigned)bf16rne(rb) << 16);
}
__device__ __forceinline__ void split2(float a, float b, unsigned& hi, unsigned& lo) {
    unsigned short ha = bf16rne(a), hb = bf16rne(b);
    hi = (unsigned)ha | ((unsigned)hb << 16);
    float ra = a - __uint_as_float((unsigned)ha << 16);
    float rb = b - __uint_as_float((unsigned)hb << 16);
    lo = (unsigned)bf16rne(ra) | ((unsigned)bf16rne(rb) << 16);
}

// cheap in-register split: hi = trunc-bf16(v), lo = trunc-bf16(v - hi).
// |v - hi - lo| <= 2^-16 |v| (vs 2^-17 for double-rne) — negligible downstream.
__device__ __forceinline__ void tsplit2(float a, float b, unsigned& h, unsigned& l) {
    unsigned ua = __float_as_uint(a), ub = __float_as_uint(b);
    h = (ua >> 16) | (ub & 0xFFFF0000u);
    float ra = a - __uint_as_float(ua & 0xFFFF0000u);
    float rb = b - __uint_as_float(ub & 0xFFFF0000u);
    l = (__float_as_uint(ra) >> 16) | (__float_as_uint(rb) & 0xFFFF0000u);
}
__device__ __forceinline__ void split8(float4 a, float4 b, bf16x8& h8, bf16x8& l8) {
    uint4 h, l;
    tsplit2(a.x, a.y, h.x, l.x);
    tsplit2(a.z, a.w, h.y, l.y);
    tsplit2(b.x, b.y, h.z, l.z);
    tsplit2(b.z, b.w, h.w, l.w);
    h8 = __builtin_bit_cast(bf16x8, h);
    l8 = __builtin_bit_cast(bf16x8, l);
}

// ---------------- setup: W -> hi/lo bf16 chunk images ----------------
// layout: [chunk][node][koct][16B]  (byte off = c*16384 + node*64 + koct*16)
__global__ void wsplit_k(const float* __restrict__ W,
                         unsigned int* __restrict__ whi, unsigned int* __restrict__ wlo) {
    int gid = blockIdx.x * 512 + threadIdx.x;      // 0..8191
    int n   = gid >> 5;                            // node 0..255
    int oct = gid & 31;                            // k-octet
    float4 a = make_float4(0.f,0.f,0.f,0.f), b = a;
    if (n < N_INNER) {
        a = *(const float4*)(W + (size_t)n * IN_DIM + oct * 8);
        b = *(const float4*)(W + (size_t)n * IN_DIM + oct * 8 + 4);
    }
    uint4 h, l;
    split2(a.x, a.y, h.x, l.x); split2(a.z, a.w, h.y, l.y);
    split2(b.x, b.y, h.z, l.z); split2(b.z, b.w, h.w, l.w);
    int c = oct >> 2, koct = oct & 3;
    size_t off = (size_t)c * 4096 + (size_t)n * 16 + koct * 4;   // uints
    *(uint4*)(whi + off) = h;
    *(uint4*)(wlo + off) = l;
}

// ---------------- setup: Q = softmax(leaf), transposed hi/lo bf16 ----------------
__global__ void qt_k(const float* __restrict__ leaf,
                     unsigned short* __restrict__ qhi, unsigned short* __restrict__ qlo) {
    int l = threadIdx.x;                           // leaf 0..255
    const float* row = leaf + l * OUT_DIM;
    float v[OUT_DIM];
    float mx = -1e30f;
#pragma unroll
    for (int o = 0; o < OUT_DIM; ++o) { v[o] = row[o]; mx = fmaxf(mx, v[o]); }
    float s = 0.f;
#pragma unroll
    for (int o = 0; o < OUT_DIM; ++o) { v[o] = __expf(v[o] - mx); s += v[o]; }
    float r = 1.f / s;
#pragma unroll
    for (int o = 0; o < OUT_DIM; ++o) {
        float q = v[o] * r;
        unsigned short h = bf16rne(q);
        float res = q - __uint_as_float((unsigned)h << 16);
        qhi[o * 256 + l] = h;
        qlo[o * 256 + l] = bf16rne(res);
    }
}

// tree DP stage (qq = top-3 leaf bits), u16 fixed-point probs
#define TREE_STAGE(D) { \
    const int base_ = (1 << (D)) - 1 + (qq << ((D) - 3)); \
    _Pragma("unroll") \
    for (int i = (1 << ((D) - 3)) - 1; i >= 0; --i) { \
        float pr_ = (float)pb[base_ + i] * INV64K; \
        float a_  = P[i]; \
        float lv_ = a_ * pr_; \
        P[2*i]     = lv_; \
        P[2*i + 1] = a_ - lv_; \
    } }

#define MFMA_BF16(A, B, C) __builtin_amdgcn_mfma_f32_16x16x32_bf16(A, B, C, 0, 0, 0)

// ---------------- fused main kernel ----------------
// Main GEMM is barrier-free: W fragments register-direct from the pre-split
// global image (coalesced 1KB/instr, L1/L2-resident); x register-direct with
// in-reg trunc split. LDS is used only by the tail (prob + P images).
__launch_bounds__(NTHR, 4)
__global__ void tree_k(const float* __restrict__ x,
                       const float* __restrict__ bv, const float* __restrict__ beta,
                       const unsigned short* __restrict__ qhi, const unsigned short* __restrict__ qlo,
                       const char* __restrict__ wimg_hi, const char* __restrict__ wimg_lo,
                       float* __restrict__ out) {
    extern __shared__ char smem[];
    const int tid  = threadIdx.x;
    const int row0 = blockIdx.x * TILE_M;

    const int lane  = tid & 63;
    const int w     = tid >> 6;          // wave 0..7
    const int col16 = lane & 15;
    const int hi4   = lane >> 4;         // k-octet 0..3
    const int wr    = w >> 2;            // row group (2)
    const int wc    = w & 3;             // col group (4)

    f32x4 acc[2][4];
#pragma unroll
    for (int i = 0; i < 2; ++i)
#pragma unroll
        for (int j = 0; j < 4; ++j) acc[i][j] = (f32x4){0.f, 0.f, 0.f, 0.f};

    // per-lane A source rows: wr*32 + rf*16 + col16, k-octet hi4
    const float* xp0 = x + (size_t)(row0 + wr * 32 + col16) * IN_DIM + hi4 * 8;
    const float* xp1 = xp0 + (size_t)16 * IN_DIM;
    // per-lane B base: node = wc*64 + cf*16 + col16, koct = hi4
    const int bbase = (wc * 64 + col16) * 64 + hi4 * 16;

    // A prefetch (chunk 0)
    float4 a00 = *(const float4*)(xp0);
    float4 a01 = *(const float4*)(xp0 + 4);
    float4 a10 = *(const float4*)(xp1);
    float4 a11 = *(const float4*)(xp1 + 4);

#pragma unroll 1
    for (int c = 0; c < NCHUNK; ++c) {
        // B loads first (cover latency with the splits below)
        const char* bhp = wimg_hi + (size_t)c * 16384 + bbase;
        const char* blp = wimg_lo + (size_t)c * 16384 + bbase;
        bf16x8 bh[4], bl[4];
#pragma unroll
        for (int cf = 0; cf < 4; ++cf) {
            bh[cf] = *(const bf16x8*)(bhp + cf * 1024);
            bl[cf] = *(const bf16x8*)(blp + cf * 1024);
        }
        // split current A (VALU, overlaps B latency)
        bf16x8 ah0, al0, ah1, al1;
        split8(a00, a01, ah0, al0);
        split8(a10, a11, ah1, al1);
        // prefetch next A
        if (c + 1 < NCHUNK) {
            a00 = *(const float4*)(xp0 + (c + 1) * BK);
            a01 = *(const float4*)(xp0 + (c + 1) * BK + 4);
            a10 = *(const float4*)(xp1 + (c + 1) * BK);
            a11 = *(const float4*)(xp1 + (c + 1) * BK + 4);
        }
#pragma unroll
        for (int cf = 0; cf < 4; ++cf) {
            acc[0][cf] = MFMA_BF16(ah0, bh[cf], acc[0][cf]);
            acc[1][cf] = MFMA_BF16(ah1, bh[cf], acc[1][cf]);
            acc[0][cf] = MFMA_BF16(ah0, bl[cf], acc[0][cf]);
            acc[1][cf] = MFMA_BF16(ah1, bl[cf], acc[1][cf]);
            acc[0][cf] = MFMA_BF16(al0, bh[cf], acc[0][cf]);
            acc[1][cf] = MFMA_BF16(al1, bh[cf], acc[1][cf]);
        }
    }

    // ---- epilogue: prob = sigmoid(beta*(logit+b)) -> u16 LDS [64][PSTR] ----
    unsigned short* prob = (unsigned short*)smem;
    {
        float bb[4], bt[4];
#pragma unroll
        for (int cf = 0; cf < 4; ++cf) {
            int col = wc * 64 + cf * 16 + col16;
            bb[cf] = (col < N_INNER) ? bv[col]   : 0.f;
            bt[cf] = (col < N_INNER) ? beta[col] : 0.f;
        }
#pragma unroll
        for (int rf = 0; rf < 2; ++rf)
#pragma unroll
            for (int cf = 0; cf < 4; ++cf) {
                int col = wc * 64 + cf * 16 + col16;
#pragma unroll
                for (int r = 0; r < 4; ++r) {
                    int row = wr * 32 + rf * 16 + hi4 * 4 + r;
                    float t = (acc[rf][cf][r] + bb[cf]) * bt[cf];
                    float s = 1.f / (1.f + __expf(-t));
                    float u = fminf(s * 65536.f + 0.5f, 65535.f);
                    prob[row * PSTR + col] = (unsigned short)(unsigned)u;
                }
            }
    }
    __syncthreads();                 // B0: prob visible

    // ---- tree expansion: 8 threads/row, 32 leaves each ----
    const int prow = tid >> 3;
    const int qq   = tid & 7;
    const unsigned short* pb = prob + prow * PSTR;
    float P[32];
    {
        float p0 = (float)pb[0] * INV64K;             float f0 = (qq & 4) ? (1.f - p0) : p0;
        float p1 = (float)pb[1 + (qq >> 2)] * INV64K; float f1 = (qq & 2) ? (1.f - p1) : p1;
        float p2 = (float)pb[3 + (qq >> 1)] * INV64K; float f2 = (qq & 1) ? (1.f - p2) : p2;
        P[0] = f0 * f1 * f2;
    }
    TREE_STAGE(3) TREE_STAGE(4) TREE_STAGE(5) TREE_STAGE(6) TREE_STAGE(7)

    // p -> global (output 1)
    {
        float* po = out + OUT_HDR + (size_t)(row0 + prow) * N_LEAF + qq * 32;
#pragma unroll
        for (int m = 0; m < 8; ++m)
            *(float4*)(po + m * 4) = make_float4(P[4*m], P[4*m+1], P[4*m+2], P[4*m+3]);
    }

    // ---- P lo-image (exclusive LDS region — no barrier needed before writes) ----
#pragma unroll
    for (int kg = 0; kg < 4; ++kg) {
        uint4 l;
        l.x = packlo2(P[kg*8+0], P[kg*8+1]);
        l.y = packlo2(P[kg*8+2], P[kg*8+3]);
        l.z = packlo2(P[kg*8+4], P[kg*8+5]);
        l.w = packlo2(P[kg*8+6], P[kg*8+7]);
        *(uint4*)(smem + IMG_LO + qq * 4096 + kg * 1024 + ((prow * 16) ^ (qq << 4))) = l;
    }
    __syncthreads();                 // B1: prob reads done + lo image visible

    // ---- P hi-image overlaying prob ----
#pragma unroll
    for (int kg = 0; kg < 4; ++kg) {
        uint4 h;
        h.x = packhi2(P[kg*8+0], P[kg*8+1]);
        h.y = packhi2(P[kg*8+2], P[kg*8+3]);
        h.z = packhi2(P[kg*8+4], P[kg*8+5]);
        h.w = packhi2(P[kg*8+6], P[kg*8+7]);
        *(uint4*)(smem + qq * 4096 + kg * 1024 + ((prow * 16) ^ (qq << 4))) = h;
    }
    __syncthreads();                 // B2: hi image visible

    // ---- out = p @ Q via MFMA; single merged pass (hi*(Qh+Ql) + lo*Qh) ----
    f32x4 acc2 = (f32x4){0.f,0.f,0.f,0.f};
    const int cfw  = w >> 2;             // 0: cols 0..15, 1: cols 16..31
    const int arow = (w & 3) * 16 + col16;
    const int qcol = (cfw * 16 + col16) * 256;

#pragma unroll
    for (int kc = 0; kc < 8; ++kc) {
        const int po = kc * 4096 + hi4 * 1024 + ((arow * 16) ^ (kc << 4));
        bf16x8 ph = *(const bf16x8*)(smem + po);
        bf16x8 pl = *(const bf16x8*)(smem + IMG_LO + po);
        int qo = qcol + kc * 32 + hi4 * 8;
        bf16x8 qbh = *(const bf16x8*)(qhi + qo);
        bf16x8 qbl = *(const bf16x8*)(qlo + qo);
        acc2 = MFMA_BF16(ph, qbh, acc2);
        acc2 = MFMA_BF16(ph, qbl, acc2);
        acc2 = MFMA_BF16(pl, qbh, acc2);
    }
#pragma unroll
    for (int r = 0; r < 4; ++r) {
        int row = (w & 3) * 16 + hi4 * 4 + r;
        out[(size_t)(row0 + row) * OUT_DIM + cfw * 16 + col16] = acc2[r];
    }
}

extern "C" void kernel_launch(void* const* d_in, const int* in_sizes, int n_in,
                              void* d_out, int out_size, void* d_ws, size_t ws_size,
                              hipStream_t stream) {
    const float* x    = (const float*)d_in[0];
    const float* W    = (const float*)d_in[1];
    const float* bv   = (const float*)d_in[2];
    const float* beta = (const float*)d_in[3];
    const float* leaf = (const float*)d_in[4];
    float* out = (float*)d_out;
    char* ws = (char*)d_ws;

    unsigned short* qhi = (unsigned short*)(ws + WS_QT_HI);
    unsigned short* qlo = (unsigned short*)(ws + WS_QT_LO);
    char* whi = ws + WS_WIMG_HI;
    char* wlo = ws + WS_WIMG_LO;

    hipFuncSetAttribute(reinterpret_cast<const void*>(tree_k),
                        hipFuncAttributeMaxDynamicSharedMemorySize, SMEM_BYTES);

    wsplit_k<<<16, 512, 0, stream>>>(W, (unsigned int*)whi, (unsigned int*)wlo);
    qt_k<<<1, 256, 0, stream>>>(leaf, qhi, qlo);
    tree_k<<<BATCH / TILE_M, NTHR, SMEM_BYTES, stream>>>(
        x, bv, beta, qhi, qlo, whi, wlo, out);
}

// Round 2
// 148.202 us; speedup vs baseline: 1.3535x; 1.3535x over previous
//
#include <hip/hip_runtime.h>

#define BATCH   131072
#define IN_DIM  256
#define OUT_DIM 32
#define N_INNER 255
#define N_LEAF  256
#define OUT_HDR (BATCH * OUT_DIM)

#define TILE_M  64
#define BK      32
#define NTHR    512
#define NCHUNK  8
#define PSTR    260                      // u16; 4-row stride = +8 banks -> conflict-free prob writes
#define INV64K  (1.0f / 65536.0f)

// ---- d_ws layout (bytes) ----
#define WS_QT_HI   0                     // [32 cols][256 leaves] bf16
#define WS_QT_LO   16384
#define WS_WIMG_HI 32768                 // [8 chunk][4 kg][256 node][16B] bf16-hi
#define WS_WIMG_LO (32768 + 131072)      // same layout, bf16-lo

// ---- LDS layout (bytes) ----
// main loop (double-buffered):
//   WB0 [0,32768)       W chunk buf 0: hi 16K ([kg][node][16B]) + lo 16K
//   WB1 [32768,65536)   W chunk buf 1
//   XB0 [65536,73728)   x chunk buf 0: hi 4K ([kg][row][16B]) + lo 4K
//   XB1 [73728,81920)   x chunk buf 1
// tail (after final barrier, all main bufs dead):
//   prob u16 [64][PSTR] at 0            (33280 B)
//   P_hi image [0,32768)                (overlays prob, after B1)
//   P_lo image [34816,67584)            (exclusive, written pre-B1)
#define WB0 0
#define WB1 32768
#define XB0 65536
#define XB1 73728
#define IMG_LO 34816
#define SMEM_BYTES 81920                 // 80 KB -> 2 blocks/CU

typedef __attribute__((ext_vector_type(8))) short bf16x8;
typedef __attribute__((ext_vector_type(4))) float f32x4;

__device__ __forceinline__ unsigned short bf16rne(float a) {
    unsigned u = __float_as_uint(a);
    return (unsigned short)((u + 0x7FFFu + ((u >> 16) & 1u)) >> 16);
}
__device__ __forceinline__ unsigned packhi2(float a, float b) {
    return (unsigned)bf16rne(a) | ((unsigned)bf16rne(b) << 16);
}
__device__ __forceinline__ unsigned packlo2(float a, float b) {
    unsigned short ha = bf16rne(a), hb = bf16rne(b);
    float ra = a - __uint_as_float((unsigned)ha << 16);
    float rb = b - __uint_as_float((unsigned)hb << 16);
    return (unsigned)bf16rne(ra) | ((unsigned)bf16rne(rb) << 16);
}
__device__ __forceinline__ void split2(float a, float b, unsigned& hi, unsigned& lo) {
    unsigned short ha = bf16rne(a), hb = bf16rne(b);
    hi = (unsigned)ha | ((unsigned)hb << 16);
    float ra = a - __uint_as_float((unsigned)ha << 16);
    float rb = b - __uint_as_float((unsigned)hb << 16);
    lo = (unsigned)bf16rne(ra) | ((unsigned)bf16rne(rb) << 16);
}
// cheap trunc split (proven numerically OK in round 1)
__device__ __forceinline__ void tsplit2(float a, float b, unsigned& h, unsigned& l) {
    unsigned ua = __float_as_uint(a), ub = __float_as_uint(b);
    h = (ua >> 16) | (ub & 0xFFFF0000u);
    float ra = a - __uint_as_float(ua & 0xFFFF0000u);
    float rb = b - __uint_as_float(ub & 0xFFFF0000u);
    l = (__float_as_uint(ra) >> 16) | (__float_as_uint(rb) & 0xFFFF0000u);
}

__device__ __forceinline__ void gload16(const void* g, void* l) {
    __builtin_amdgcn_global_load_lds(
        (const __attribute__((address_space(1))) unsigned int*)g,
        (__attribute__((address_space(3))) unsigned int*)l, 16, 0, 0);
}

// ---------------- setup: W -> hi/lo bf16 chunk images ----------------
// image layout: [chunk][kg][node][16B]  (matches linear gload_lds staging)
__global__ void wsplit_k(const float* __restrict__ W,
                         unsigned int* __restrict__ whi, unsigned int* __restrict__ wlo) {
    int gid = blockIdx.x * 512 + threadIdx.x;      // 0..8191
    int n   = gid >> 5;                            // node 0..255
    int oct = gid & 31;                            // k-octet
    float4 a = make_float4(0.f,0.f,0.f,0.f), b = a;
    if (n < N_INNER) {
        a = *(const float4*)(W + (size_t)n * IN_DIM + oct * 8);
        b = *(const float4*)(W + (size_t)n * IN_DIM + oct * 8 + 4);
    }
    uint4 h, l;
    split2(a.x, a.y, h.x, l.x); split2(a.z, a.w, h.y, l.y);
    split2(b.x, b.y, h.z, l.z); split2(b.z, b.w, h.w, l.w);
    int c = oct >> 2, kg = oct & 3;
    size_t off = ((size_t)(c * 4 + kg) * 256 + n) * 4;   // uints
    *(uint4*)(whi + off) = h;
    *(uint4*)(wlo + off) = l;
}

// ---------------- setup: Q = softmax(leaf), transposed hi/lo bf16 ----------------
__global__ void qt_k(const float* __restrict__ leaf,
                     unsigned short* __restrict__ qhi, unsigned short* __restrict__ qlo) {
    int l = threadIdx.x;                           // leaf 0..255
    const float* row = leaf + l * OUT_DIM;
    float v[OUT_DIM];
    float mx = -1e30f;
#pragma unroll
    for (int o = 0; o < OUT_DIM; ++o) { v[o] = row[o]; mx = fmaxf(mx, v[o]); }
    float s = 0.f;
#pragma unroll
    for (int o = 0; o < OUT_DIM; ++o) { v[o] = __expf(v[o] - mx); s += v[o]; }
    float r = 1.f / s;
#pragma unroll
    for (int o = 0; o < OUT_DIM; ++o) {
        float q = v[o] * r;
        unsigned short h = bf16rne(q);
        float res = q - __uint_as_float((unsigned)h << 16);
        qhi[o * 256 + l] = h;
        qlo[o * 256 + l] = bf16rne(res);
    }
}

// tree DP stage (qq = top-3 leaf bits), u16 fixed-point probs
#define TREE_STAGE(D) { \
    const int base_ = (1 << (D)) - 1 + (qq << ((D) - 3)); \
    _Pragma("unroll") \
    for (int i = (1 << ((D) - 3)) - 1; i >= 0; --i) { \
        float pr_ = (float)pb[base_ + i] * INV64K; \
        float a_  = P[i]; \
        float lv_ = a_ * pr_; \
        P[2*i]     = lv_; \
        P[2*i + 1] = a_ - lv_; \
    } }

#define MFMA_BF16(A, B, C) __builtin_amdgcn_mfma_f32_16x16x32_bf16(A, B, C, 0, 0, 0)

// ---------------- fused main kernel ----------------
// T3-min pipeline: STAGE(c+1 -> other buf) issued BEFORE compute(c); the
// vmcnt(0) drain that __syncthreads forces lands AFTER the 24 MFMAs, so
// stage latency overlaps compute. One barrier per chunk.
__launch_bounds__(NTHR, 4)
__global__ void tree_k(const float* __restrict__ x,
                       const float* __restrict__ bv, const float* __restrict__ beta,
                       const unsigned short* __restrict__ qhi, const unsigned short* __restrict__ qlo,
                       const char* __restrict__ wimg_hi, const char* __restrict__ wimg_lo,
                       float* __restrict__ out) {
    extern __shared__ char smem[];
    const int tid  = threadIdx.x;
    const int row0 = blockIdx.x * TILE_M;

    const int lane  = tid & 63;
    const int w     = tid >> 6;          // wave 0..7
    const int col16 = lane & 15;
    const int hi4   = lane >> 4;         // k-group 0..3
    const int wr    = w >> 2;            // row group
    const int wc    = w & 3;             // col group

    f32x4 acc[2][4];
#pragma unroll
    for (int i = 0; i < 2; ++i)
#pragma unroll
        for (int j = 0; j < 4; ++j) acc[i][j] = (f32x4){0.f, 0.f, 0.f, 0.f};

    const int xrow = tid >> 3;
    const int xkq  = tid & 7;
    const int xoff = (xkq >> 1) * 1024 + xrow * 16 + (xkq & 1) * 8;
    const float* xsrc = x + (size_t)(row0 + xrow) * IN_DIM + xkq * 4;

    // ---- prologue: stage chunk 0 into buf 0 ----
    {
        char* dh = smem + WB0 + w * 1024;
        char* dl = dh + 16384;
        gload16(wimg_hi + tid * 16,        dh);
        gload16(wimg_hi + 8192 + tid * 16, dh + 8192);
        gload16(wimg_lo + tid * 16,        dl);
        gload16(wimg_lo + 8192 + tid * 16, dl + 8192);
        float4 v = *(const float4*)(xsrc);
        uint2 h, l;
        tsplit2(v.x, v.y, h.x, l.x);
        tsplit2(v.z, v.w, h.y, l.y);
        *(uint2*)(smem + XB0 + xoff)        = h;
        *(uint2*)(smem + XB0 + 4096 + xoff) = l;
    }
    __syncthreads();

#pragma unroll 1
    for (int c = 0; c < NCHUNK; ++c) {
        const int cur = c & 1;
        const char* wb = smem + (cur ? WB1 : WB0);
        const char* xb = smem + (cur ? XB1 : XB0);
        char* wbn = smem + (cur ? WB0 : WB1);
        char* xbn = smem + (cur ? XB0 : XB1);

        // ---- issue next-chunk stage (into the other buffer) ----
        float4 xn;
        const bool more = (c + 1 < NCHUNK);
        if (more) {
            const char* gh = wimg_hi + (size_t)(c + 1) * 16384;
            const char* gl = wimg_lo + (size_t)(c + 1) * 16384;
            char* dh = wbn + w * 1024;
            char* dl = dh + 16384;
            gload16(gh + tid * 16,        dh);
            gload16(gh + 8192 + tid * 16, dh + 8192);
            gload16(gl + tid * 16,        dl);
            gload16(gl + 8192 + tid * 16, dl + 8192);
            xn = *(const float4*)(xsrc + (c + 1) * BK);
        }

        // ---- compute chunk c from current buffers ----
        bf16x8 ah[2], al[2];
#pragma unroll
        for (int rf = 0; rf < 2; ++rf) {
            int ao = hi4 * 1024 + (wr * 32 + rf * 16 + col16) * 16;
            ah[rf] = *(const bf16x8*)(xb + ao);
            al[rf] = *(const bf16x8*)(xb + 4096 + ao);
        }
#pragma unroll
        for (int cf = 0; cf < 4; ++cf) {
            int bo = hi4 * 4096 + (wc * 64 + cf * 16 + col16) * 16;
            bf16x8 bh = *(const bf16x8*)(wb + bo);
            bf16x8 bl = *(const bf16x8*)(wb + 16384 + bo);
#pragma unroll
            for (int rf = 0; rf < 2; ++rf) {
                acc[rf][cf] = MFMA_BF16(ah[rf], bh, acc[rf][cf]);
                acc[rf][cf] = MFMA_BF16(ah[rf], bl, acc[rf][cf]);
                acc[rf][cf] = MFMA_BF16(al[rf], bh, acc[rf][cf]);
            }
        }

        // ---- finish next-chunk x staging (after MFMAs; hides x load latency) ----
        if (more) {
            uint2 h, l;
            tsplit2(xn.x, xn.y, h.x, l.x);
            tsplit2(xn.z, xn.w, h.y, l.y);
            *(uint2*)(xbn + xoff)        = h;
            *(uint2*)(xbn + 4096 + xoff) = l;
        }
        __syncthreads();             // drains W(c+1) gload_lds + x write; aligns waves
    }

    // ---- epilogue: prob = sigmoid(beta*(logit+b)) -> u16 LDS [64][PSTR] ----
    unsigned short* prob = (unsigned short*)smem;
    {
        float bb[4], bt[4];
#pragma unroll
        for (int cf = 0; cf < 4; ++cf) {
            int col = wc * 64 + cf * 16 + col16;
            bb[cf] = (col < N_INNER) ? bv[col]   : 0.f;
            bt[cf] = (col < N_INNER) ? beta[col] : 0.f;
        }
#pragma unroll
        for (int rf = 0; rf < 2; ++rf)
#pragma unroll
            for (int cf = 0; cf < 4; ++cf) {
                int col = wc * 64 + cf * 16 + col16;
#pragma unroll
                for (int r = 0; r < 4; ++r) {
                    int row = wr * 32 + rf * 16 + hi4 * 4 + r;
                    float t = (acc[rf][cf][r] + bb[cf]) * bt[cf];
                    float s = 1.f / (1.f + __expf(-t));
                    float u = fminf(s * 65536.f + 0.5f, 65535.f);
                    prob[row * PSTR + col] = (unsigned short)(unsigned)u;
                }
            }
    }
    __syncthreads();                 // B0: prob visible

    // ---- tree expansion: 8 threads/row, 32 leaves each ----
    const int prow = tid >> 3;
    const int qq   = tid & 7;
    const unsigned short* pb = prob + prow * PSTR;
    float P[32];
    {
        float p0 = (float)pb[0] * INV64K;             float f0 = (qq & 4) ? (1.f - p0) : p0;
        float p1 = (float)pb[1 + (qq >> 2)] * INV64K; float f1 = (qq & 2) ? (1.f - p1) : p1;
        float p2 = (float)pb[3 + (qq >> 1)] * INV64K; float f2 = (qq & 1) ? (1.f - p2) : p2;
        P[0] = f0 * f1 * f2;
    }
    TREE_STAGE(3) TREE_STAGE(4) TREE_STAGE(5) TREE_STAGE(6) TREE_STAGE(7)

    // p -> global (output 1)
    {
        float* po = out + OUT_HDR + (size_t)(row0 + prow) * N_LEAF + qq * 32;
#pragma unroll
        for (int m = 0; m < 8; ++m)
            *(float4*)(po + m * 4) = make_float4(P[4*m], P[4*m+1], P[4*m+2], P[4*m+3]);
    }

    // ---- P lo-image (exclusive region [34816,67584) — safe to write pre-B1) ----
#pragma unroll
    for (int kg = 0; kg < 4; ++kg) {
        uint4 l;
        l.x = packlo2(P[kg*8+0], P[kg*8+1]);
        l.y = packlo2(P[kg*8+2], P[kg*8+3]);
        l.z = packlo2(P[kg*8+4], P[kg*8+5]);
        l.w = packlo2(P[kg*8+6], P[kg*8+7]);
        *(uint4*)(smem + IMG_LO + qq * 4096 + kg * 1024 + ((prow * 16) ^ (qq << 4))) = l;
    }
    __syncthreads();                 // B1: prob reads done + lo image visible

    // ---- P hi-image overlaying prob ----
#pragma unroll
    for (int kg = 0; kg < 4; ++kg) {
        uint4 h;
        h.x = packhi2(P[kg*8+0], P[kg*8+1]);
        h.y = packhi2(P[kg*8+2], P[kg*8+3]);
        h.z = packhi2(P[kg*8+4], P[kg*8+5]);
        h.w = packhi2(P[kg*8+6], P[kg*8+7]);
        *(uint4*)(smem + qq * 4096 + kg * 1024 + ((prow * 16) ^ (qq << 4))) = h;
    }
    __syncthreads();                 // B2: hi image visible

    // ---- out = p @ Q via MFMA; single merged pass (hi*(Qh+Ql) + lo*Qh) ----
    f32x4 acc2 = (f32x4){0.f,0.f,0.f,0.f};
    const int cfw  = w >> 2;             // 0: cols 0..15, 1: cols 16..31
    const int arow = (w & 3) * 16 + col16;
    const int qcol = (cfw * 16 + col16) * 256;

#pragma unroll
    for (int kc = 0; kc < 8; ++kc) {
        const int po = kc * 4096 + hi4 * 1024 + ((arow * 16) ^ (kc << 4));
        bf16x8 ph = *(const bf16x8*)(smem + po);
        bf16x8 pl = *(const bf16x8*)(smem + IMG_LO + po);
        int qo = qcol + kc * 32 + hi4 * 8;
        bf16x8 qbh = *(const bf16x8*)(qhi + qo);
        bf16x8 qbl = *(const bf16x8*)(qlo + qo);
        acc2 = MFMA_BF16(ph, qbh, acc2);
        acc2 = MFMA_BF16(ph, qbl, acc2);
        acc2 = MFMA_BF16(pl, qbh, acc2);
    }
#pragma unroll
    for (int r = 0; r < 4; ++r) {
        int row = (w & 3) * 16 + hi4 * 4 + r;
        out[(size_t)(row0 + row) * OUT_DIM + cfw * 16 + col16] = acc2[r];
    }
}

extern "C" void kernel_launch(void* const* d_in, const int* in_sizes, int n_in,
                              void* d_out, int out_size, void* d_ws, size_t ws_size,
                              hipStream_t stream) {
    const float* x    = (const float*)d_in[0];
    const float* W    = (const float*)d_in[1];
    const float* bv   = (const float*)d_in[2];
    const float* beta = (const float*)d_in[3];
    const float* leaf = (const float*)d_in[4];
    float* out = (float*)d_out;
    char* ws = (char*)d_ws;

    unsigned short* qhi = (unsigned short*)(ws + WS_QT_HI);
    unsigned short* qlo = (unsigned short*)(ws + WS_QT_LO);
    char* whi = ws + WS_WIMG_HI;
    char* wlo = ws + WS_WIMG_LO;

    hipFuncSetAttribute(reinterpret_cast<const void*>(tree_k),
                        hipFuncAttributeMaxDynamicSharedMemorySize, SMEM_BYTES);

    wsplit_k<<<16, 512, 0, stream>>>(W, (unsigned int*)whi, (unsigned int*)wlo);
    qt_k<<<1, 256, 0, stream>>>(leaf, qhi, qlo);
    tree_k<<<BATCH / TILE_M, NTHR, SMEM_BYTES, stream>>>(
        x, bv, beta, qhi, qlo, whi, wlo, out);
}